// Round 4
// baseline (231.680 us; speedup 1.0000x reference)
//
#include <hip/hip_runtime.h>

#define NN 50000
#define NE 1600000
#define FDIM 128
#define CDIM 128              // H*D
#define NGRAPH 16
#define SLOPE 0.2f
#define CSTRIDE 96            // CSR slots/node (ushort); deg=1+Poisson(32), +11 sigma safe
#define BINSH 7               // bin = dst >> 7 (128 nodes per bin)
#define NBIN 391              // ceil(50000/128)
#define EPB 6400              // edges per bin-role block
#define NB1 250               // 1600000 / 6400 exactly
#define EPT 25                // edges per thread in bin role
#define CAP 5120              // gstage slots per bin (mean 4096, +16 sigma)
#define POOL_NODES 64
#define POOL_NB ((NN + POOL_NODES - 1) / POOL_NODES)
#define TNB 782               // ceil(NN/64) transform-role blocks
#define LOG2E 1.4426950408889634f

// f32 -> bf16 round-to-nearest-even (no NaN inputs here) — used for MFMA frags
__device__ __forceinline__ unsigned short f2bf(float f) {
    unsigned u = __float_as_uint(f);
    return (unsigned short)((u + 0x7FFFu + ((u >> 16) & 1u)) >> 16);
}
__device__ __forceinline__ unsigned packbf(float a, float b) {
    return (unsigned)f2bf(a) | ((unsigned)f2bf(b) << 16);
}
// f32 -> f16 (RNE). f16 beats bf16 precision here (|xl|,|xr| < ~4 << 65504)
__device__ __forceinline__ unsigned short f2h(float f) {
    union { _Float16 h; unsigned short u; } c;
    c.h = (_Float16)f;
    return c.u;
}

typedef __attribute__((ext_vector_type(8))) short short8;   // 8 bf16 = 4 VGPR
typedef __attribute__((ext_vector_type(4))) float f32x4;
typedef _Float16 h2 __attribute__((ext_vector_type(2)));    // packed f16 pair
union FragU { uint4 u; short8 s; };
union HU    { uint4 u; h2 h[4]; };
union HI    { h2 h; int i; };

// quad_perm DPP add: d += d[lane^mask] for mask in {1,2} — pure VALU, no LDS.
__device__ __forceinline__ float qadd_xor1(float d) {
#if __has_builtin(__builtin_amdgcn_update_dpp)
    int x = __builtin_amdgcn_update_dpp(0, __float_as_int(d), 0xB1, 0xF, 0xF, true);
    return d + __int_as_float(x);
#else
    return d + __shfl_xor(d, 1);
#endif
}
__device__ __forceinline__ float qadd_xor2(float d) {
#if __has_builtin(__builtin_amdgcn_update_dpp)
    int x = __builtin_amdgcn_update_dpp(0, __float_as_int(d), 0x4E, 0xF, 0xF, true);
    return d + __int_as_float(x);
#else
    return d + __shfl_xor(d, 2);
#endif
}
__device__ __forceinline__ float exp2fast(float d) {
#if __has_builtin(__builtin_amdgcn_exp2f)
    return __builtin_amdgcn_exp2f(d);
#else
    return __expf(d * 0.6931471805599453f);
#endif
}

// -------- init: zero pooled output + bin counters + PACK W (r17) -----------
__global__ __launch_bounds__(256) void k_init(
    float* __restrict__ out, int* __restrict__ gbin_cnt,
    const float* __restrict__ Wl, const float* __restrict__ Wr,
    uint4* __restrict__ wpack) {
    const int b = blockIdx.x;
    if (b < 16) {
        int C = b * 256 + threadIdx.x;          // 0..4095
        const float* W = (C < 2048) ? Wl : Wr;
        int c = C & 2047;
        int ccol = c & 15, cq = (c >> 4) & 3, ckq = (c >> 6) & 3, cnt_ = c >> 8;
        const float* wp = &W[(size_t)(ckq * 32 + cq * 8) * CDIM + cnt_ * 16 + ccol];
        uint4 u;
        u.x = packbf(wp[0],        wp[CDIM]);
        u.y = packbf(wp[2*CDIM],   wp[3*CDIM]);
        u.z = packbf(wp[4*CDIM],   wp[5*CDIM]);
        u.w = packbf(wp[6*CDIM],   wp[7*CDIM]);
        wpack[C] = u;
    } else {
        int i = (b - 16) * 256 + threadIdx.x;
        if (i < NGRAPH * CDIM) out[i] = 0.f;
        if (i < NBIN) gbin_cnt[i] = 0;
    }
}

// -------- fused front: edge binning ∪ MFMA transform (block-role split) ----
// r18: transform role reads B-fragments straight from L2-hot wpack (64KB,
// coalesced 1KB/instr) — drops the 32KB LDS staging + 4 barriers + 64
// ds_read_b128 per thread that r10-r17 carried.
__global__ __launch_bounds__(256) void k_front(
    const float* __restrict__ x,
    const float* __restrict__ bl, const float* __restrict__ br,
    const int* __restrict__ src, const int* __restrict__ dst,
    int* __restrict__ gbin_cnt, unsigned* __restrict__ gstage,
    unsigned short* __restrict__ xlh, unsigned short* __restrict__ xrh,
    const uint4* __restrict__ wpack) {
    __shared__ __align__(16) char shraw[32768];
    const int tid = threadIdx.x;

    if (blockIdx.x < NB1) {
        // ================= bin role (r7 counting-sort phase 1) =============
        int* bcnt = (int*)shraw;          // [NBIN]
        int* boff = bcnt + NBIN;          // [NBIN]
        int* gb   = boff + NBIN;          // [NBIN]
        int* sc   = gb + NBIN;            // [256]
        unsigned* st = (unsigned*)(sc + 256);   // [EPB]
        const int t  = tid;
        const int e0 = blockIdx.x * EPB;

        for (int b = t; b < NBIN; b += 256) bcnt[b] = 0;
        __syncthreads();

        unsigned sd[EPT]; int bn[EPT]; int pl[EPT];
#pragma unroll
        for (int k = 0; k < EPT; k++) {
            int e = e0 + k * 256 + t;
            int s = src[e], d = dst[e];
            bn[k] = d >> BINSH;
            sd[k] = (unsigned)s | ((unsigned)(d & 127) << 16)
                                | ((unsigned)bn[k] << 23);
            pl[k] = atomicAdd(&bcnt[bn[k]], 1);
        }
        __syncthreads();

        // exclusive scan of bcnt (chunks of 2 + Hillis-Steele on 256)
        int c0 = (2*t     < NBIN) ? bcnt[2*t]     : 0;
        int c1 = (2*t + 1 < NBIN) ? bcnt[2*t + 1] : 0;
        int v  = c0 + c1;
        sc[t] = v; __syncthreads();
        for (int off = 1; off < 256; off <<= 1) {
            int add = (t >= off) ? sc[t - off] : 0;
            __syncthreads();
            sc[t] += add;
            __syncthreads();
        }
        int base = sc[t] - v;
        if (2*t     < NBIN) boff[2*t]     = base;
        if (2*t + 1 < NBIN) boff[2*t + 1] = base + c0;
        __syncthreads();

        for (int b = t; b < NBIN; b += 256) {
            int c = bcnt[b];
            gb[b] = (c > 0) ? atomicAdd(&gbin_cnt[b], c) : 0;
        }
#pragma unroll
        for (int k = 0; k < EPT; k++) st[boff[bn[k]] + pl[k]] = sd[k];
        __syncthreads();

        for (int idx = t; idx < EPB; idx += 256) {
            unsigned w = st[idx];
            int b = w >> 23;
            int p = gb[b] + (idx - boff[b]);
            if (p < CAP) gstage[(size_t)b * CAP + p] = w;
        }
    } else {
        // ================= transform role (r10 MFMA, r18 no-LDS B) =========
        const int bid   = blockIdx.x - NB1;
        const int wv    = tid >> 6;
        const int lane  = tid & 63;
        const int quad  = lane >> 4;
        const int col   = lane & 15;
        const int node0 = bid * 64;
        const int nodeA = node0 + wv * 16 + col;
        const bool aval = nodeA < NN;

        FragU afrag[4];
#pragma unroll
        for (int kq = 0; kq < 4; kq++) {
            float4 lo = make_float4(0.f,0.f,0.f,0.f), hi = lo;
            if (aval) {
                const float* ap = &x[(size_t)nodeA * FDIM + kq * 32 + quad * 8];
                lo = *(const float4*)ap;
                hi = *(const float4*)(ap + 4);
            }
            afrag[kq].u.x = packbf(lo.x, lo.y);
            afrag[kq].u.y = packbf(lo.z, lo.w);
            afrag[kq].u.z = packbf(hi.x, hi.y);
            afrag[kq].u.w = packbf(hi.z, hi.w);
        }

        const int myrow0 = node0 + wv * 16 + quad * 4;

#pragma unroll
        for (int mat = 0; mat < 2; mat++) {
            const float* bb = mat ? br : bl;
            unsigned short* dsto = mat ? xrh : xlh;
            const uint4* wsrc = wpack + mat * 2048;

#pragma unroll
            for (int nt = 0; nt < 8; nt++) {
                f32x4 acc = {0.f, 0.f, 0.f, 0.f};
#pragma unroll
                for (int kq = 0; kq < 4; kq++) {
                    FragU bfr;
                    bfr.u = wsrc[(nt * 4 + kq) * 64 + lane];   // L2-hot, coalesced
                    acc = __builtin_amdgcn_mfma_f32_16x16x32_bf16(
                              afrag[kq].s, bfr.s, acc, 0, 0, 0);
                }
                int ch = nt * 16 + col;
                float bv = bb[ch];
#pragma unroll
                for (int r = 0; r < 4; r++) {
                    int node = myrow0 + r;
                    if (node < NN)
                        dsto[(size_t)node * CDIM + ch] = f2h(acc[r] + bv);
                }
            }
        }
    }
}

// -------- phase 2: build padded ushort CSR per bin ------------------------
__global__ __launch_bounds__(512) void k_csr(
    const int* __restrict__ gbin_cnt, const unsigned* __restrict__ gstage,
    int* __restrict__ cnt, unsigned short* __restrict__ colp) {
    __shared__ int nfill[128];
    __shared__ unsigned short crow[128 * CSTRIDE];   // 24.5 KB
    const int bin = blockIdx.x;
    const int t   = threadIdx.x;
    const int n0  = bin << BINSH;
    const int nb  = min(128, NN - n0);
    const int m   = min(gbin_cnt[bin], CAP);

    if (t < 128) nfill[t] = 0;
    __syncthreads();

    unsigned w[10];                         // CAP/512 = 10
    bool     ok[10];
#pragma unroll
    for (int k = 0; k < 10; k++) {
        int i = k * 512 + t;
        ok[k] = i < m;
        if (ok[k]) w[k] = gstage[(size_t)bin * CAP + i];
    }
#pragma unroll
    for (int k = 0; k < 10; k++) {
        if (ok[k]) {
            int dl = (w[k] >> 16) & 127;
            int p  = atomicAdd(&nfill[dl], 1);
            if (p < CSTRIDE - 1)
                crow[dl * CSTRIDE + p] = (unsigned short)(w[k] & 0xFFFF);
        }
    }
    __syncthreads();

    if (t < nb) {
        int c = min(nfill[t], CSTRIDE - 1);
        crow[t * CSTRIDE + c] = (unsigned short)(n0 + t);  // self loop last
        cnt[n0 + t] = c + 1;
    }
    __syncthreads();

    // coalesced slice copy (uint-packed), bin slice contiguous in colp
    unsigned* gout = (unsigned*)colp + (size_t)bin * (128 * CSTRIDE / 2);
    const unsigned* cin = (const unsigned*)crow;
    for (int idx = t; idx < 128 * CSTRIDE / 2; idx += 512) gout[idx] = cin[idx];
}

// ---------------- per-node attention aggregation (f16 packed path) ---------
// One wave per destination node (50K independent waves).  r15/r16: f16
// features -> packed-f16 VALU logit path; pool NOT fused (r16 atomic-storm).
// r18: (a) full prefetch — f0 <= 16 always, so ALL <=16 gather rows load
// up-front into q[16] (static idx, rule-#20-safe): 16 loads in flight per
// wave, converts residual latency stalls to VALU issue; (b) att pre-scaled
// by log2e -> v_exp_f32 directly (2^x native); (c) packed-f16 accumulate
// (4 v_pk_fma_f16 replace 8 v_fma_mix; +~3e-4 abs error, negligible).
__device__ __forceinline__ void edge_compute(
    uint4 qu,
    const h2* __restrict__ rx, const h2* __restrict__ ah,
    float& s, h2* __restrict__ acch) {
    HU q; q.u = qu;
    const h2 c02 = {(_Float16)SLOPE, (_Float16)SLOPE};
    float d = 0.f;
#pragma unroll
    for (int k = 0; k < 4; k++) {
        h2 t  = q.h[k] + rx[k];                          // v_pk_add_f16
        h2 lk = __builtin_elementwise_max(t, t * c02);   // leaky: max(t,0.2t)
#if __has_builtin(__builtin_amdgcn_fdot2)
        d = __builtin_amdgcn_fdot2(lk, ah[k], d, false); // v_dot2_f32_f16
#else
        d = fmaf((float)lk.x, (float)ah[k].x, d);
        d = fmaf((float)lk.y, (float)ah[k].y, d);
#endif
    }
    d = qadd_xor1(d);
    d = qadd_xor2(d);                      // per-head logit (DPP, no LDS)
    float w = exp2fast(d);                 // ah pre-scaled by log2e
    s += w;
    _Float16 wh = (_Float16)w;
    h2 w2 = {wh, wh};
#pragma unroll
    for (int k = 0; k < 4; k++)            // v_pk_fma_f16
        acch[k] += w2 * q.h[k];
}

__device__ __forceinline__ void edge_body(
    const char* __restrict__ xlb, unsigned chb, int j,
    const h2* __restrict__ rx, const h2* __restrict__ ah,
    float& s, h2* __restrict__ acch) {
    uint4 qu = *(const uint4*)(xlb + (((unsigned)j << 8) | chb));
    edge_compute(qu, rx, ah, s, acch);
}

__global__ __launch_bounds__(256) void k_aggregate(
    const unsigned short* __restrict__ xlh, const unsigned short* __restrict__ xrh,
    const float* __restrict__ att, const float* __restrict__ bias,
    const int* __restrict__ cnt, const unsigned short* __restrict__ colp,
    float* __restrict__ nodeout) {
    const int wave = blockIdx.x * 4 + (threadIdx.x >> 6);
    const int lane = threadIdx.x & 63;
    const int i     = wave;                 // grid = NN/4 exactly
    const size_t start = (size_t)i * CSTRIDE;
    const int deg   = cnt[i];
    const int grp   = lane >> 4;
    const int ch0   = (lane & 15) * 8;
    const unsigned chb = (unsigned)(ch0 * 2);
    const char* xlb = (const char*)xlh;

    // cols once, unguarded: rows are CSTRIDE-padded, slots >= deg unused
    int cj0 = (int)colp[start + lane];
    int cj1 = 0;
    if (deg > 64) cj1 = (int)colp[start + 64 + lane];  // rare, wave-uniform

    HU rxu;
    rxu.u = *(const uint4*)&xrh[(size_t)i * CDIM + ch0];
    const float4 aa0 = *(const float4*)&att[ch0];
    const float4 aa1 = *(const float4*)&att[ch0 + 4];
    h2 ah[4];                                      // att * log2e (exp2 domain)
    ah[0] = h2{(_Float16)(aa0.x*LOG2E), (_Float16)(aa0.y*LOG2E)};
    ah[1] = h2{(_Float16)(aa0.z*LOG2E), (_Float16)(aa0.w*LOG2E)};
    ah[2] = h2{(_Float16)(aa1.x*LOG2E), (_Float16)(aa1.y*LOG2E)};
    ah[3] = h2{(_Float16)(aa1.z*LOG2E), (_Float16)(aa1.w*LOG2E)};

    float s = 0.f;
    h2 acch[4];
#pragma unroll
    for (int k = 0; k < 4; k++) acch[k] = h2{(_Float16)0.f, (_Float16)0.f};

    const int full = deg >> 2;
    const int f0   = full < 16 ? full : 16;

    // -------- full-prefetch guard-free main loop (r18) --------
    uint4 q[16];
#pragma unroll
    for (int k = 0; k < 16; k++) {
        if (k < f0) {                        // wave-uniform guard
            int j = __shfl(cj0, k * 4 + grp);
            q[k] = *(const uint4*)(xlb + (((unsigned)j << 8) | chb));
        }
    }
#pragma unroll
    for (int k = 0; k < 16; k++) {
        if (k < f0)
            edge_compute(q[k], rxu.h, ah, s, acch);
    }

    for (int t = 16; t < full; t++) {       // deg > 64: vanishing probability
        int j = __shfl(cj1, t * 4 + grp - 64);
        edge_body(xlb, chb, j, rxu.h, ah, s, acch);
    }
    // tail (<= 3 edges): shfl CONVERGENT (r12 lesson), guard body only
    int e  = full * 4 + grp;
    int jt = (e < 64) ? __shfl(cj0, e) : __shfl(cj1, (e - 64) & 63);
    if (e < deg)
        edge_body(xlb, chb, jt, rxu.h, ah, s, acch);

    // merge the 4 group-states: plain sums (no rescale needed)
#pragma unroll
    for (int dist = 16; dist <= 32; dist <<= 1) {
        s += __shfl_xor(s, dist);
#pragma unroll
        for (int k = 0; k < 4; k++) {
            HI a, b;
            a.h = acch[k];
            b.i = __shfl_xor(a.i, dist);
            acch[k] = a.h + b.h;
        }
    }

    if (grp == 0) {
        float inv = 1.f / s;
        float4 o0, o1;
        const float4 b0 = *(const float4*)&bias[ch0];
        const float4 b1 = *(const float4*)&bias[ch0 + 4];
        o0.x = fmaxf(fmaf((float)acch[0].x, inv, b0.x), 0.f);
        o0.y = fmaxf(fmaf((float)acch[0].y, inv, b0.y), 0.f);
        o0.z = fmaxf(fmaf((float)acch[1].x, inv, b0.z), 0.f);
        o0.w = fmaxf(fmaf((float)acch[1].y, inv, b0.w), 0.f);
        o1.x = fmaxf(fmaf((float)acch[2].x, inv, b1.x), 0.f);
        o1.y = fmaxf(fmaf((float)acch[2].y, inv, b1.y), 0.f);
        o1.z = fmaxf(fmaf((float)acch[3].x, inv, b1.z), 0.f);
        o1.w = fmaxf(fmaf((float)acch[3].y, inv, b1.w), 0.f);
        float* op = &nodeout[(size_t)i * CDIM + ch0];
        *(float4*)op       = o0;
        *(float4*)(op + 4) = o1;
    }
}

// ---------------- global max pool, exploiting sorted batch -----------------
__global__ __launch_bounds__(256) void k_pool(
    const float* __restrict__ nodeout, const int* __restrict__ batch,
    float* __restrict__ out) {
    const int tid  = threadIdx.x;
    const int c4   = (tid & 31) * 4;
    const int nl   = tid >> 5;            // 0..7
    const int base = blockIdx.x * POOL_NODES;
    float4 mx = make_float4(0.f, 0.f, 0.f, 0.f);
    int cur = -1;
#pragma unroll
    for (int k = 0; k < POOL_NODES / 8; k++) {
        int node = base + k * 8 + nl;
        if (node >= NN) break;
        int g = batch[node];
        if (g != cur) {
            if (cur >= 0) {
                int* op = (int*)&out[cur * CDIM + c4];
                if (mx.x > 0.f) atomicMax(op,     __float_as_int(mx.x));
                if (mx.y > 0.f) atomicMax(op + 1, __float_as_int(mx.y));
                if (mx.z > 0.f) atomicMax(op + 2, __float_as_int(mx.z));
                if (mx.w > 0.f) atomicMax(op + 3, __float_as_int(mx.w));
            }
            cur = g;
            mx = make_float4(0.f, 0.f, 0.f, 0.f);
        }
        float4 v = *(const float4*)&nodeout[(size_t)node * CDIM + c4];
        mx.x = fmaxf(mx.x, v.x);
        mx.y = fmaxf(mx.y, v.y);
        mx.z = fmaxf(mx.z, v.z);
        mx.w = fmaxf(mx.w, v.w);
    }
    if (cur >= 0) {
        int* op = (int*)&out[cur * CDIM + c4];
        if (mx.x > 0.f) atomicMax(op,     __float_as_int(mx.x));
        if (mx.y > 0.f) atomicMax(op + 1, __float_as_int(mx.y));
        if (mx.z > 0.f) atomicMax(op + 2, __float_as_int(mx.z));
        if (mx.w > 0.f) atomicMax(op + 3, __float_as_int(mx.w));
    }
}

extern "C" void kernel_launch(void* const* d_in, const int* in_sizes, int n_in,
                              void* d_out, int out_size, void* d_ws, size_t ws_size,
                              hipStream_t stream) {
    const float* x     = (const float*)d_in[0];
    const int*   ei    = (const int*)d_in[1];
    const int*   batch = (const int*)d_in[2];
    const float* Wl    = (const float*)d_in[3];
    const float* bl    = (const float*)d_in[4];
    const float* Wr    = (const float*)d_in[5];
    const float* br    = (const float*)d_in[6];
    const float* att   = (const float*)d_in[7];
    const float* bias  = (const float*)d_in[8];
    float* out = (float*)d_out;

    char* w = (char*)d_ws;
    float*          nodeout  = (float*)w;          w += (size_t)NN * CDIM * 4;
    unsigned short* xlh      = (unsigned short*)w; w += (size_t)NN * CDIM * 2;
    unsigned short* xrh      = (unsigned short*)w; w += (size_t)NN * CDIM * 2;
    int*            cnt      = (int*)w;            w += (size_t)NN * 4;
    unsigned short* colp     = (unsigned short*)w; w += (size_t)NBIN * 128 * CSTRIDE * 2;
    unsigned*       gstage   = (unsigned*)w;       w += (size_t)NBIN * CAP * 4;
    int*            gbin_cnt = (int*)w;            w += (size_t)NBIN * 4;
    uint4*          wpack    = (uint4*)w;          w += (size_t)4096 * 16;

    const int* src = ei;
    const int* dst = ei + NE;

    k_init<<<26, 256, 0, stream>>>(out, gbin_cnt, Wl, Wr, wpack);
    k_front<<<NB1 + TNB, 256, 0, stream>>>(x, bl, br,
                                           src, dst, gbin_cnt, gstage, xlh, xrh,
                                           wpack);
    k_csr<<<NBIN, 512, 0, stream>>>(gbin_cnt, gstage, cnt, colp);
    k_aggregate<<<NN / 4, 256, 0, stream>>>(xlh, xrh, att, bias,
                                            cnt, colp, nodeout);
    k_pool<<<POOL_NB, 256, 0, stream>>>(nodeout, batch, out);
}

// Round 6
// 226.251 us; speedup vs baseline: 1.0240x; 1.0240x over previous
//
#include <hip/hip_runtime.h>

#define NN 50000
#define NE 1600000
#define FDIM 128
#define CDIM 128              // H*D
#define NGRAPH 16
#define SLOPE 0.2f
#define CSTRIDE 96            // CSR slots/node (ushort); deg=1+Poisson(32), +11 sigma safe
#define BINSH 7               // bin = dst >> 7 (128 nodes per bin)
#define NBIN 391              // ceil(50000/128)
#define EPB 6400              // edges per bin-role block
#define NB1 250               // 1600000 / 6400 exactly
#define EPT 25                // edges per thread in bin role
#define CAP 5120              // gstage slots per bin (mean 4096, +16 sigma)
#define POOL_NODES 64
#define POOL_NB ((NN + POOL_NODES - 1) / POOL_NODES)
#define TNB 782               // ceil(NN/64) transform-role blocks
#define LOG2E 1.4426950408889634f

// r19 LESSON (FAILED, absmax 0.33): direct per-edge atomic scatter of USHORT
// colp slots from many blocks is NOT safe — concurrent sub-dword stores to
// shared lines across XCDs lost data. Keep all cross-block scatters
// dword-granular and bin-partitioned (this counting-sort pipeline).

// f32 -> bf16 round-to-nearest-even (no NaN inputs here) — used for MFMA frags
__device__ __forceinline__ unsigned short f2bf(float f) {
    unsigned u = __float_as_uint(f);
    return (unsigned short)((u + 0x7FFFu + ((u >> 16) & 1u)) >> 16);
}
__device__ __forceinline__ unsigned packbf(float a, float b) {
    return (unsigned)f2bf(a) | ((unsigned)f2bf(b) << 16);
}
// f32 -> f16 (RNE). f16 beats bf16 precision here (|xl|,|xr| < ~4 << 65504)
__device__ __forceinline__ unsigned short f2h(float f) {
    union { _Float16 h; unsigned short u; } c;
    c.h = (_Float16)f;
    return c.u;
}

typedef __attribute__((ext_vector_type(8))) short short8;   // 8 bf16 = 4 VGPR
typedef __attribute__((ext_vector_type(4))) float f32x4;
typedef _Float16 h2 __attribute__((ext_vector_type(2)));    // packed f16 pair
union FragU { uint4 u; short8 s; };
union HU    { uint4 u; h2 h[4]; };
union HI    { h2 h; int i; };

// quad_perm DPP add: d += d[lane^mask] for mask in {1,2} — pure VALU, no LDS.
__device__ __forceinline__ float qadd_xor1(float d) {
#if __has_builtin(__builtin_amdgcn_update_dpp)
    int x = __builtin_amdgcn_update_dpp(0, __float_as_int(d), 0xB1, 0xF, 0xF, true);
    return d + __int_as_float(x);
#else
    return d + __shfl_xor(d, 1);
#endif
}
__device__ __forceinline__ float qadd_xor2(float d) {
#if __has_builtin(__builtin_amdgcn_update_dpp)
    int x = __builtin_amdgcn_update_dpp(0, __float_as_int(d), 0x4E, 0xF, 0xF, true);
    return d + __int_as_float(x);
#else
    return d + __shfl_xor(d, 2);
#endif
}
__device__ __forceinline__ float exp2fast(float d) {
#if __has_builtin(__builtin_amdgcn_exp2f)
    return __builtin_amdgcn_exp2f(d);
#else
    return __expf(d * 0.6931471805599453f);
#endif
}

// -------- init: zero pooled output + bin counters + PACK W (r17) -----------
__global__ __launch_bounds__(256) void k_init(
    float* __restrict__ out, int* __restrict__ gbin_cnt,
    const float* __restrict__ Wl, const float* __restrict__ Wr,
    uint4* __restrict__ wpack) {
    const int b = blockIdx.x;
    if (b < 16) {
        int C = b * 256 + threadIdx.x;          // 0..4095
        const float* W = (C < 2048) ? Wl : Wr;
        int c = C & 2047;
        int ccol = c & 15, cq = (c >> 4) & 3, ckq = (c >> 6) & 3, cnt_ = c >> 8;
        const float* wp = &W[(size_t)(ckq * 32 + cq * 8) * CDIM + cnt_ * 16 + ccol];
        uint4 u;
        u.x = packbf(wp[0],        wp[CDIM]);
        u.y = packbf(wp[2*CDIM],   wp[3*CDIM]);
        u.z = packbf(wp[4*CDIM],   wp[5*CDIM]);
        u.w = packbf(wp[6*CDIM],   wp[7*CDIM]);
        wpack[C] = u;
    } else {
        int i = (b - 16) * 256 + threadIdx.x;
        if (i < NGRAPH * CDIM) out[i] = 0.f;
        if (i < NBIN) gbin_cnt[i] = 0;
    }
}

// -------- fused front: edge binning ∪ MFMA transform (block-role split) ----
__global__ __launch_bounds__(256) void k_front(
    const float* __restrict__ x,
    const float* __restrict__ bl, const float* __restrict__ br,
    const int* __restrict__ src, const int* __restrict__ dst,
    int* __restrict__ gbin_cnt, unsigned* __restrict__ gstage,
    unsigned short* __restrict__ xlh, unsigned short* __restrict__ xrh,
    const uint4* __restrict__ wpack) {
    __shared__ __align__(16) char shraw[32768];
    const int tid = threadIdx.x;

    if (blockIdx.x < NB1) {
        // ================= bin role (r7 counting-sort phase 1) =============
        int* bcnt = (int*)shraw;          // [NBIN]
        int* boff = bcnt + NBIN;          // [NBIN]
        int* gb   = boff + NBIN;          // [NBIN]
        int* sc   = gb + NBIN;            // [256]
        unsigned* st = (unsigned*)(sc + 256);   // [EPB]
        const int t  = tid;
        const int e0 = blockIdx.x * EPB;

        for (int b = t; b < NBIN; b += 256) bcnt[b] = 0;
        __syncthreads();

        unsigned sd[EPT]; int bn[EPT]; int pl[EPT];
#pragma unroll
        for (int k = 0; k < EPT; k++) {
            int e = e0 + k * 256 + t;
            int s = src[e], d = dst[e];
            bn[k] = d >> BINSH;
            sd[k] = (unsigned)s | ((unsigned)(d & 127) << 16)
                                | ((unsigned)bn[k] << 23);
            pl[k] = atomicAdd(&bcnt[bn[k]], 1);
        }
        __syncthreads();

        // exclusive scan of bcnt (chunks of 2 + Hillis-Steele on 256)
        int c0 = (2*t     < NBIN) ? bcnt[2*t]     : 0;
        int c1 = (2*t + 1 < NBIN) ? bcnt[2*t + 1] : 0;
        int v  = c0 + c1;
        sc[t] = v; __syncthreads();
        for (int off = 1; off < 256; off <<= 1) {
            int add = (t >= off) ? sc[t - off] : 0;
            __syncthreads();
            sc[t] += add;
            __syncthreads();
        }
        int base = sc[t] - v;
        if (2*t     < NBIN) boff[2*t]     = base;
        if (2*t + 1 < NBIN) boff[2*t + 1] = base + c0;
        __syncthreads();

        for (int b = t; b < NBIN; b += 256) {
            int c = bcnt[b];
            gb[b] = (c > 0) ? atomicAdd(&gbin_cnt[b], c) : 0;
        }
#pragma unroll
        for (int k = 0; k < EPT; k++) st[boff[bn[k]] + pl[k]] = sd[k];
        __syncthreads();

        for (int idx = t; idx < EPB; idx += 256) {
            unsigned w = st[idx];
            int b = w >> 23;
            int p = gb[b] + (idx - boff[b]);
            if (p < CAP) gstage[(size_t)b * CAP + p] = w;
        }
    } else {
        // ================= transform role (r10 MFMA) =======================
        uint4* wfrag = (uint4*)shraw;     // [2048] = 32 KB
        const int bid   = blockIdx.x - NB1;
        const int wv    = tid >> 6;
        const int lane  = tid & 63;
        const int quad  = lane >> 4;
        const int col   = lane & 15;
        const int node0 = bid * 64;
        const int nodeA = node0 + wv * 16 + col;
        const bool aval = nodeA < NN;

        FragU afrag[4];
#pragma unroll
        for (int kq = 0; kq < 4; kq++) {
            float4 lo = make_float4(0.f,0.f,0.f,0.f), hi = lo;
            if (aval) {
                const float* ap = &x[(size_t)nodeA * FDIM + kq * 32 + quad * 8];
                lo = *(const float4*)ap;
                hi = *(const float4*)(ap + 4);
            }
            afrag[kq].u.x = packbf(lo.x, lo.y);
            afrag[kq].u.y = packbf(lo.z, lo.w);
            afrag[kq].u.z = packbf(hi.x, hi.y);
            afrag[kq].u.w = packbf(hi.z, hi.w);
        }

        const int myrow0 = node0 + wv * 16 + quad * 4;

        for (int mat = 0; mat < 2; mat++) {
            const float* bb = mat ? br : bl;
            unsigned short* dsto = mat ? xrh : xlh;
            const uint4* wsrc = wpack + mat * 2048;
            __syncthreads();
#pragma unroll
            for (int i = 0; i < 8; i++)          // prepacked: plain 16B copy
                wfrag[i * 256 + tid] = wsrc[i * 256 + tid];
            __syncthreads();

#pragma unroll
            for (int nt = 0; nt < 8; nt++) {
                f32x4 acc = {0.f, 0.f, 0.f, 0.f};
#pragma unroll
                for (int kq = 0; kq < 4; kq++) {
                    FragU bfr;
                    bfr.u = wfrag[(nt * 4 + kq) * 64 + lane];
                    acc = __builtin_amdgcn_mfma_f32_16x16x32_bf16(
                              afrag[kq].s, bfr.s, acc, 0, 0, 0);
                }
                int ch = nt * 16 + col;
                float bv = bb[ch];
#pragma unroll
                for (int r = 0; r < 4; r++) {
                    int node = myrow0 + r;
                    if (node < NN)
                        dsto[(size_t)node * CDIM + ch] = f2h(acc[r] + bv);
                }
            }
        }
    }
}

// -------- phase 2: build padded ushort CSR per bin ------------------------
// Single block per bin: all colp writes are dword-packed from ONE block —
// no cross-block sub-dword hazard (r19 lesson).
__global__ __launch_bounds__(512) void k_csr(
    const int* __restrict__ gbin_cnt, const unsigned* __restrict__ gstage,
    int* __restrict__ cnt, unsigned short* __restrict__ colp) {
    __shared__ int nfill[128];
    __shared__ unsigned short crow[128 * CSTRIDE];   // 24.5 KB
    const int bin = blockIdx.x;
    const int t   = threadIdx.x;
    const int n0  = bin << BINSH;
    const int nb  = min(128, NN - n0);
    const int m   = min(gbin_cnt[bin], CAP);

    if (t < 128) nfill[t] = 0;
    __syncthreads();

    unsigned w[10];                         // CAP/512 = 10
    bool     ok[10];
#pragma unroll
    for (int k = 0; k < 10; k++) {
        int i = k * 512 + t;
        ok[k] = i < m;
        if (ok[k]) w[k] = gstage[(size_t)bin * CAP + i];
    }
#pragma unroll
    for (int k = 0; k < 10; k++) {
        if (ok[k]) {
            int dl = (w[k] >> 16) & 127;
            int p  = atomicAdd(&nfill[dl], 1);
            if (p < CSTRIDE - 1)
                crow[dl * CSTRIDE + p] = (unsigned short)(w[k] & 0xFFFF);
        }
    }
    __syncthreads();

    if (t < nb) {
        int c = min(nfill[t], CSTRIDE - 1);
        crow[t * CSTRIDE + c] = (unsigned short)(n0 + t);  // self loop last
        cnt[n0 + t] = c + 1;
    }
    __syncthreads();

    // coalesced slice copy (uint-packed), bin slice contiguous in colp
    unsigned* gout = (unsigned*)colp + (size_t)bin * (128 * CSTRIDE / 2);
    const unsigned* cin = (const unsigned*)crow;
    for (int idx = t; idx < 128 * CSTRIDE / 2; idx += 512) gout[idx] = cin[idx];
}

// ---------------- per-node attention aggregation (f16 packed path) ---------
// One wave per destination node (50K independent waves).  r15/r16: f16
// features -> packed-f16 VALU logit path; pool NOT fused (r16 atomic-storm).
// r17: DPP head-reduce + depth-2 software pipeline.  r18 lessons: q[16]
// full prefetch REGRESSED (compiler chunked it, VALUBusy 73->49) — depth-2
// is the sweet spot; exp2-prescaled att + packed-f16 accumulate are KEPT
// (passed with absmax unchanged 0.00390625 — floor is f16 feature storage).
__device__ __forceinline__ void edge_compute(
    uint4 qu,
    const h2* __restrict__ rx, const h2* __restrict__ ah,
    float& s, h2* __restrict__ acch) {
    HU q; q.u = qu;
    const h2 c02 = {(_Float16)SLOPE, (_Float16)SLOPE};
    float d = 0.f;
#pragma unroll
    for (int k = 0; k < 4; k++) {
        h2 t  = q.h[k] + rx[k];                          // v_pk_add_f16
        h2 lk = __builtin_elementwise_max(t, t * c02);   // leaky: max(t,0.2t)
#if __has_builtin(__builtin_amdgcn_fdot2)
        d = __builtin_amdgcn_fdot2(lk, ah[k], d, false); // v_dot2_f32_f16
#else
        d = fmaf((float)lk.x, (float)ah[k].x, d);
        d = fmaf((float)lk.y, (float)ah[k].y, d);
#endif
    }
    d = qadd_xor1(d);
    d = qadd_xor2(d);                      // per-head logit (DPP, no LDS)
    float w = exp2fast(d);                 // ah pre-scaled by log2e
    s += w;
    _Float16 wh = (_Float16)w;
    h2 w2 = {wh, wh};
#pragma unroll
    for (int k = 0; k < 4; k++)            // v_pk_fma_f16
        acch[k] += w2 * q.h[k];
}

__device__ __forceinline__ void edge_body(
    const char* __restrict__ xlb, unsigned chb, int j,
    const h2* __restrict__ rx, const h2* __restrict__ ah,
    float& s, h2* __restrict__ acch) {
    uint4 qu = *(const uint4*)(xlb + (((unsigned)j << 8) | chb));
    edge_compute(qu, rx, ah, s, acch);
}

__global__ __launch_bounds__(256) void k_aggregate(
    const unsigned short* __restrict__ xlh, const unsigned short* __restrict__ xrh,
    const float* __restrict__ att, const float* __restrict__ bias,
    const int* __restrict__ cnt, const unsigned short* __restrict__ colp,
    float* __restrict__ nodeout) {
    const int wave = blockIdx.x * 4 + (threadIdx.x >> 6);
    const int lane = threadIdx.x & 63;
    const int i     = wave;                 // grid = NN/4 exactly
    const size_t start = (size_t)i * CSTRIDE;
    const int deg   = cnt[i];
    const int grp   = lane >> 4;
    const int ch0   = (lane & 15) * 8;
    const unsigned chb = (unsigned)(ch0 * 2);
    const char* xlb = (const char*)xlh;

    // cols once, unguarded: rows are CSTRIDE-padded, slots >= deg unused
    int cj0 = (int)colp[start + lane];
    int cj1 = 0;
    if (deg > 64) cj1 = (int)colp[start + 64 + lane];  // rare, wave-uniform

    HU rxu;
    rxu.u = *(const uint4*)&xrh[(size_t)i * CDIM + ch0];
    const float4 aa0 = *(const float4*)&att[ch0];
    const float4 aa1 = *(const float4*)&att[ch0 + 4];
    h2 ah[4];                                      // att * log2e (exp2 domain)
    ah[0] = h2{(_Float16)(aa0.x*LOG2E), (_Float16)(aa0.y*LOG2E)};
    ah[1] = h2{(_Float16)(aa0.z*LOG2E), (_Float16)(aa0.w*LOG2E)};
    ah[2] = h2{(_Float16)(aa1.x*LOG2E), (_Float16)(aa1.y*LOG2E)};
    ah[3] = h2{(_Float16)(aa1.z*LOG2E), (_Float16)(aa1.w*LOG2E)};

    float s = 0.f;
    h2 acch[4];
#pragma unroll
    for (int k = 0; k < 4; k++) acch[k] = h2{(_Float16)0.f, (_Float16)0.f};

    const int full = deg >> 2;
    const int f0   = full < 16 ? full : 16;

    // -------- depth-2 pipelined guard-free main loop (r17) --------
    if (f0 > 0) {
        int ja = __shfl(cj0, grp);
        uint4 qa = *(const uint4*)(xlb + (((unsigned)ja << 8) | chb));
        if (f0 > 1) {
            int jb = __shfl(cj0, 4 + grp);
            uint4 qb = *(const uint4*)(xlb + (((unsigned)jb << 8) | chb));
            for (int t = 0; t + 2 < f0; t++) {
                int jc = __shfl(cj0, (t + 2) * 4 + grp);
                uint4 qc = *(const uint4*)(xlb + (((unsigned)jc << 8) | chb));
                edge_compute(qa, rxu.h, ah, s, acch);
                qa = qb; qb = qc;
            }
            edge_compute(qa, rxu.h, ah, s, acch);
            edge_compute(qb, rxu.h, ah, s, acch);
        } else {
            edge_compute(qa, rxu.h, ah, s, acch);
        }
    }
    for (int t = 16; t < full; t++) {       // deg > 64: vanishing probability
        int j = __shfl(cj1, t * 4 + grp - 64);
        edge_body(xlb, chb, j, rxu.h, ah, s, acch);
    }
    // tail (<= 3 edges): shfl CONVERGENT (r12 lesson), guard body only
    int e  = full * 4 + grp;
    int jt = (e < 64) ? __shfl(cj0, e) : __shfl(cj1, (e - 64) & 63);
    if (e < deg)
        edge_body(xlb, chb, jt, rxu.h, ah, s, acch);

    // merge the 4 group-states: plain sums (no rescale needed)
#pragma unroll
    for (int dist = 16; dist <= 32; dist <<= 1) {
        s += __shfl_xor(s, dist);
#pragma unroll
        for (int k = 0; k < 4; k++) {
            HI a, b;
            a.h = acch[k];
            b.i = __shfl_xor(a.i, dist);
            acch[k] = a.h + b.h;
        }
    }

    if (grp == 0) {
        float inv = 1.f / s;
        float4 o0, o1;
        const float4 b0 = *(const float4*)&bias[ch0];
        const float4 b1 = *(const float4*)&bias[ch0 + 4];
        o0.x = fmaxf(fmaf((float)acch[0].x, inv, b0.x), 0.f);
        o0.y = fmaxf(fmaf((float)acch[0].y, inv, b0.y), 0.f);
        o0.z = fmaxf(fmaf((float)acch[1].x, inv, b0.z), 0.f);
        o0.w = fmaxf(fmaf((float)acch[1].y, inv, b0.w), 0.f);
        o1.x = fmaxf(fmaf((float)acch[2].x, inv, b1.x), 0.f);
        o1.y = fmaxf(fmaf((float)acch[2].y, inv, b1.y), 0.f);
        o1.z = fmaxf(fmaf((float)acch[3].x, inv, b1.z), 0.f);
        o1.w = fmaxf(fmaf((float)acch[3].y, inv, b1.w), 0.f);
        float* op = &nodeout[(size_t)i * CDIM + ch0];
        *(float4*)op       = o0;
        *(float4*)(op + 4) = o1;
    }
}

// ---------------- global max pool, exploiting sorted batch -----------------
__global__ __launch_bounds__(256) void k_pool(
    const float* __restrict__ nodeout, const int* __restrict__ batch,
    float* __restrict__ out) {
    const int tid  = threadIdx.x;
    const int c4   = (tid & 31) * 4;
    const int nl   = tid >> 5;            // 0..7
    const int base = blockIdx.x * POOL_NODES;
    float4 mx = make_float4(0.f, 0.f, 0.f, 0.f);
    int cur = -1;
#pragma unroll
    for (int k = 0; k < POOL_NODES / 8; k++) {
        int node = base + k * 8 + nl;
        if (node >= NN) break;
        int g = batch[node];
        if (g != cur) {
            if (cur >= 0) {
                int* op = (int*)&out[cur * CDIM + c4];
                if (mx.x > 0.f) atomicMax(op,     __float_as_int(mx.x));
                if (mx.y > 0.f) atomicMax(op + 1, __float_as_int(mx.y));
                if (mx.z > 0.f) atomicMax(op + 2, __float_as_int(mx.z));
                if (mx.w > 0.f) atomicMax(op + 3, __float_as_int(mx.w));
            }
            cur = g;
            mx = make_float4(0.f, 0.f, 0.f, 0.f);
        }
        float4 v = *(const float4*)&nodeout[(size_t)node * CDIM + c4];
        mx.x = fmaxf(mx.x, v.x);
        mx.y = fmaxf(mx.y, v.y);
        mx.z = fmaxf(mx.z, v.z);
        mx.w = fmaxf(mx.w, v.w);
    }
    if (cur >= 0) {
        int* op = (int*)&out[cur * CDIM + c4];
        if (mx.x > 0.f) atomicMax(op,     __float_as_int(mx.x));
        if (mx.y > 0.f) atomicMax(op + 1, __float_as_int(mx.y));
        if (mx.z > 0.f) atomicMax(op + 2, __float_as_int(mx.z));
        if (mx.w > 0.f) atomicMax(op + 3, __float_as_int(mx.w));
    }
}

extern "C" void kernel_launch(void* const* d_in, const int* in_sizes, int n_in,
                              void* d_out, int out_size, void* d_ws, size_t ws_size,
                              hipStream_t stream) {
    const float* x     = (const float*)d_in[0];
    const int*   ei    = (const int*)d_in[1];
    const int*   batch = (const int*)d_in[2];
    const float* Wl    = (const float*)d_in[3];
    const float* bl    = (const float*)d_in[4];
    const float* Wr    = (const float*)d_in[5];
    const float* br    = (const float*)d_in[6];
    const float* att   = (const float*)d_in[7];
    const float* bias  = (const float*)d_in[8];
    float* out = (float*)d_out;

    char* w = (char*)d_ws;
    float*          nodeout  = (float*)w;          w += (size_t)NN * CDIM * 4;
    unsigned short* xlh      = (unsigned short*)w; w += (size_t)NN * CDIM * 2;
    unsigned short* xrh      = (unsigned short*)w; w += (size_t)NN * CDIM * 2;
    int*            cnt      = (int*)w;            w += (size_t)NN * 4;
    unsigned short* colp     = (unsigned short*)w; w += (size_t)NBIN * 128 * CSTRIDE * 2;
    unsigned*       gstage   = (unsigned*)w;       w += (size_t)NBIN * CAP * 4;
    int*            gbin_cnt = (int*)w;            w += (size_t)NBIN * 4;
    uint4*          wpack    = (uint4*)w;          w += (size_t)4096 * 16;

    const int* src = ei;
    const int* dst = ei + NE;

    k_init<<<26, 256, 0, stream>>>(out, gbin_cnt, Wl, Wr, wpack);
    k_front<<<NB1 + TNB, 256, 0, stream>>>(x, bl, br,
                                           src, dst, gbin_cnt, gstage, xlh, xrh,
                                           wpack);
    k_csr<<<NBIN, 512, 0, stream>>>(gbin_cnt, gstage, cnt, colp);
    k_aggregate<<<NN / 4, 256, 0, stream>>>(xlh, xrh, att, bias,
                                            cnt, colp, nodeout);
    k_pool<<<POOL_NB, 256, 0, stream>>>(nodeout, batch, out);
}